// Round 1
// baseline (352.902 us; speedup 1.0000x reference)
//
#include <hip/hip_runtime.h>
#include <math.h>

// Problem constants (fixed by reference setup_inputs)
#define L0   4448   // flux length
#define NC1  16     // conv1 out channels
#define L1P  278    // after conv1(stride4,pad7)->1112 then maxpool4
#define NC2  32     // conv2 out channels
#define L2   139    // after conv2(stride2,pad3) on 278
#define NQ   8
#define NL   3
#define SD   256

// LDS strides padded for bank-conflict avoidance:
//  h1: stride 292 (292%32=4 -> 2-way max), offset +4 so pos -4..283 valid
//  h2: stride 145 (145%32=17, odd -> spread)
//  w2: stride 113 (113%32=17, odd -> spread)
#define H1_STRIDE 292
#define H2_STRIDE 145
#define W2_STRIDE 113

__global__ __launch_bounds__(256)
void aec_fused_kernel(const float* __restrict__ flux,
                      const float* __restrict__ scalars,
                      const float* __restrict__ conv1_w,
                      const float* __restrict__ bn1_g, const float* __restrict__ bn1_b,
                      const float* __restrict__ conv2_w,
                      const float* __restrict__ bn2_g, const float* __restrict__ bn2_b,
                      const float* __restrict__ proj_w1, const float* __restrict__ proj_b1,
                      const float* __restrict__ proj_w2, const float* __restrict__ proj_b2,
                      const float* __restrict__ qw,
                      const float* __restrict__ head_w1, const float* __restrict__ head_b1,
                      const float* __restrict__ head_bn_g, const float* __restrict__ head_bn_b,
                      const float* __restrict__ head_w2, const float* __restrict__ head_b2,
                      float* __restrict__ out)
{
    const int b   = blockIdx.x;
    const int tid = threadIdx.x;

    // Region A: flux staging (word w = flux idx w-8), later h2[32][145]
    __shared__ __align__(16) float A[4640];
    // Region B: h1[16][292] (+4 offset, zero pads) + slack for over-read
    __shared__ __align__(16) float Bb[4680];
    // Region C: conv2 weights [32][113], later feat[256] / cre[256] / cim[256]
    __shared__ __align__(16) float Cc[3616];
    __shared__ __align__(16) float Dw1[240];      // conv1 weights
    __shared__ __align__(16) float s_hidden[64];  // proj1 output
    __shared__ float s_red[32];
    __shared__ float s_q[8];
    __shared__ float s_hid2[32];
    __shared__ float s_U[NL * NQ * 8];            // gate matrices

    const float BN_RSQ = 0.9999950000374997f;     // 1/sqrt(1+1e-5)

    // ---------------- stage 0: stage inputs into LDS ----------------
    {
        const float4* fg = (const float4*)(flux + (size_t)b * L0);
        float4* A4 = (float4*)A;
        for (int w = tid; w < L0 / 4; w += 256) A4[2 + w] = fg[w];   // word 8+4w
        if (tid < 8) A[tid] = 0.0f;                                   // flux idx -8..-1
        if (tid >= 8 && tid < 24) A[4448 + tid] = 0.0f;               // words 4456..4471 (idx 4448..)
        for (int t = tid; t < 240; t += 256) Dw1[t] = conv1_w[t];
        for (int t = tid; t < 3584; t += 256) {
            int o = t / 112, r = t - o * 112;
            Cc[o * W2_STRIDE + r] = conv2_w[t];
        }
        // zero h1 pads: words ic*292 + {0..3} (pos -4..-1) and {286..291} (pos 282..287)
        if (tid < 160) {
            int ic = tid / 10, w = tid - ic * 10;
            int off = (w < 4) ? w : (282 + w);
            Bb[ic * H1_STRIDE + off] = 0.0f;
        }
    }
    __syncthreads();

    // ---------------- stage 1: conv1 + bn + relu + maxpool4 -> h1 ----------------
    // thread: channel c = tid&15 (weights in regs), pooled position p = (tid>>4) + 16r
    {
        const int c = tid & 15;
        const int g = tid >> 4;
        float wt[15];
        #pragma unroll
        for (int k = 0; k < 15; ++k) wt[k] = Dw1[c * 15 + k];
        const float sc = bn1_g[c] * BN_RSQ;
        const float bt = bn1_b[c];
        for (int p = g; p < L1P; p += 16) {
            // window words 16p..16p+31  (flux idx 16p-8..16p+23; used: 16p-7..16p+19)
            float win[32];
            const float4* src = (const float4*)(A + 16 * p);
            #pragma unroll
            for (int v = 0; v < 8; ++v) {
                float4 t4 = src[v];
                win[4*v+0] = t4.x; win[4*v+1] = t4.y; win[4*v+2] = t4.z; win[4*v+3] = t4.w;
            }
            float m = 0.0f;  // relu values are >= 0
            #pragma unroll
            for (int j2 = 0; j2 < 4; ++j2) {
                float acc = 0.0f;
                #pragma unroll
                for (int k = 0; k < 15; ++k) acc += win[4*j2 + 1 + k] * wt[k];
                float v = fmaxf(acc * sc + bt, 0.0f);
                m = fmaxf(m, v);
            }
            Bb[c * H1_STRIDE + 4 + p] = m;
        }
    }
    __syncthreads();

    // ---------------- stage 2: conv2 + bn + relu -> h2 in A ----------------
    // thread: c = tid&31, 18 consecutive positions j in [18g, 18g+18) (g = tid>>5)
    {
        const int c  = tid & 31;
        const int g  = tid >> 5;
        const int j0 = g * 18;
        const int nj = (g == 7) ? (L2 - 126) : 18;   // 13 for last group
        float acc[18];
        #pragma unroll
        for (int r = 0; r < 18; ++r) acc[r] = 0.0f;

        #pragma unroll 1
        for (int ic = 0; ic < 16; ++ic) {
            float wt[7];
            #pragma unroll
            for (int k = 0; k < 7; ++k) wt[k] = Cc[c * W2_STRIDE + ic * 7 + k];
            // window: pos 2j0-4 .. 2j0+39  (11 aligned float4)
            float win[44];
            const float4* src = (const float4*)(Bb + ic * H1_STRIDE + 2 * j0);
            #pragma unroll
            for (int v = 0; v < 11; ++v) {
                float4 t4 = src[v];
                win[4*v+0] = t4.x; win[4*v+1] = t4.y; win[4*v+2] = t4.z; win[4*v+3] = t4.w;
            }
            #pragma unroll
            for (int r = 0; r < 18; ++r) {
                float s = 0.0f;
                #pragma unroll
                for (int k = 0; k < 7; ++k) s += wt[k] * win[2*r + 1 + k];
                acc[r] += s;
            }
        }
        const float sc = bn2_g[c] * BN_RSQ;
        const float bt = bn2_b[c];
        #pragma unroll
        for (int r = 0; r < 18; ++r) {
            if (r < nj) {
                float v = fmaxf(acc[r] * sc + bt, 0.0f);
                A[c * H2_STRIDE + j0 + r] = v;
            }
        }
    }
    __syncthreads();

    // ---------------- gate matrices (once) ----------------
    if (tid < NL * NQ) {
        float phi = qw[tid * 3 + 0], th = qw[tid * 3 + 1], om = qw[tid * 3 + 2];
        float ch = cosf(0.5f * th), sh = sinf(0.5f * th);
        float a  = 0.5f * (phi + om), bb = 0.5f * (phi - om);
        float ca = cosf(a), sa = sinf(a), cb = cosf(bb), sb = sinf(bb);
        float* U = &s_U[tid * 8];
        U[0] =  ca * ch; U[1] = -sa * ch;   // U00
        U[2] = -cb * sh; U[3] = -sb * sh;   // U01
        U[4] =  cb * sh; U[5] = -sb * sh;   // U10
        U[6] =  ca * ch; U[7] =  sa * ch;   // U11
    }

    // ---------------- stage 3: adaptive avg pool -> feat (Cc[0..255]) ----------------
    {
        const int c = tid >> 3, i = tid & 7;
        const int s0 = (i * L2) >> 3;
        const int e0 = ((i + 1) * L2 + 7) >> 3;   // ceil
        float sum = 0.0f;
        for (int j = s0; j < e0; ++j) sum += A[c * H2_STRIDE + j];
        Cc[tid] = sum / (float)(e0 - s0);         // feat[c*8+i]
    }
    __syncthreads();

    // ---------------- stage 4: proj1 (256 -> 64), relu ----------------
    {
        const int o = tid >> 2, s = tid & 3;
        const float4* wg = (const float4*)(proj_w1 + 64 * tid);   // == o*256 + s*64
        const float4* xf = (const float4*)(Cc + 64 * s);
        float acc = 0.0f;
        #pragma unroll
        for (int t = 0; t < 16; ++t) {
            float4 w4 = wg[t], x4 = xf[t];
            acc += w4.x * x4.x + w4.y * x4.y + w4.z * x4.z + w4.w * x4.w;
        }
        acc += __shfl_down(acc, 2, 64);
        acc += __shfl_down(acc, 1, 64);
        if (s == 0) s_hidden[o] = fmaxf(acc + proj_b1[o], 0.0f);
    }
    __syncthreads();

    // ---------------- proj2 (64 -> 256) + L2 normalize -> amplitude per thread ----
    float re, im;
    {
        const float4* wg = (const float4*)(proj_w2 + 64 * tid);
        const float4* hf = (const float4*)s_hidden;
        float acc = proj_b2[tid];
        #pragma unroll
        for (int t = 0; t < 16; ++t) {
            float4 w4 = wg[t], x4 = hf[t];
            acc += w4.x * x4.x + w4.y * x4.y + w4.z * x4.z + w4.w * x4.w;
        }
        float ss = acc * acc;
        #pragma unroll
        for (int off = 32; off >= 1; off >>= 1) ss += __shfl_xor(ss, off, 64);
        if ((tid & 63) == 0) s_red[tid >> 6] = ss;
        __syncthreads();
        float sst = s_red[0] + s_red[1] + s_red[2] + s_red[3];
        float n   = sqrtf(sst);
        float inv = 1.0f / fmaxf(n, 1e-12f);
        float xi  = acc * inv;
        if (n * inv < 1e-8f) xi = 0.0625f;        // uniform 1/sqrt(256)
        re = xi; im = 0.0f;
    }

    // ---------------- quantum circuit: one amplitude per thread ----------------
    float* s_cre = &Cc[256];
    float* s_cim = &Cc[512];
    #pragma unroll 1
    for (int l = 0; l < NL; ++l) {
        #pragma unroll
        for (int q = 0; q < NQ; ++q) {
            const float* U = &s_U[(l * NQ + q) * 8];
            const float u00r = U[0], u00i = U[1], u01r = U[2], u01i = U[3];
            const float u10r = U[4], u10i = U[5], u11r = U[6], u11i = U[7];
            const int bp = 7 - q;                 // wire 0 = MSB
            float pre, pim;
            if (bp >= 6) {                        // cross-wave partner: LDS
                s_cre[tid] = re; s_cim[tid] = im;
                __syncthreads();
                const int pidx = tid ^ (1 << bp);
                pre = s_cre[pidx]; pim = s_cim[pidx];
                __syncthreads();
            } else {                              // in-wave partner: shuffle
                pre = __shfl_xor(re, 1 << bp, 64);
                pim = __shfl_xor(im, 1 << bp, 64);
            }
            const int bit = (tid >> bp) & 1;
            const float csr = bit ? u11r : u00r;
            const float csi = bit ? u11i : u00i;
            const float cpr = bit ? u10r : u01r;
            const float cpi = bit ? u10i : u01i;
            const float nr = csr * re - csi * im + cpr * pre - cpi * pim;
            const float ni = csr * im + csi * re + cpr * pim + cpi * pre;
            re = nr; im = ni;
        }
        // CNOT ring composed into one permutation: new[i] = psi[f0(f1(...f7(i)))]
        int src = tid;
        #pragma unroll
        for (int q = 7; q >= 0; --q) {
            const int cb = 7 - q;
            const int tb = 7 - ((q + 1) & 7);
            src ^= ((src >> cb) & 1) << tb;
        }
        s_cre[tid] = re; s_cim[tid] = im;
        __syncthreads();
        re = s_cre[src]; im = s_cim[src];
        __syncthreads();
    }

    // ---------------- Z expectations ----------------
    {
        const float pr = re * re + im * im;
        float zv[8];
        #pragma unroll
        for (int q = 0; q < 8; ++q) zv[q] = ((tid >> (7 - q)) & 1) ? -pr : pr;
        #pragma unroll
        for (int off = 32; off >= 1; off >>= 1) {
            #pragma unroll
            for (int q = 0; q < 8; ++q) zv[q] += __shfl_xor(zv[q], off, 64);
        }
        if ((tid & 63) == 0) {
            const int wid = tid >> 6;
            #pragma unroll
            for (int q = 0; q < 8; ++q) s_red[wid * 8 + q] = zv[q];
        }
        __syncthreads();
        if (tid < 8)
            s_q[tid] = s_red[tid] + s_red[8 + tid] + s_red[16 + tid] + s_red[24 + tid];
        __syncthreads();
    }

    // ---------------- head ----------------
    if (tid < 32) {
        float acc = head_b1[tid];
        #pragma unroll
        for (int k = 0; k < 8; ++k) acc += head_w1[tid * 14 + k] * s_q[k];
        #pragma unroll
        for (int k = 0; k < 6; ++k) acc += head_w1[tid * 14 + 8 + k] * scalars[b * 6 + k];
        float h = fmaxf(acc * (head_bn_g[tid] * BN_RSQ) + head_bn_b[tid], 0.0f);
        s_hid2[tid] = h;
    }
    __syncthreads();
    if (tid < 3) {
        float acc = head_b2[tid];
        #pragma unroll
        for (int k = 0; k < 32; ++k) acc += head_w2[tid * 32 + k] * s_hid2[k];
        out[b * 3 + tid] = acc;
    }
}

extern "C" void kernel_launch(void* const* d_in, const int* in_sizes, int n_in,
                              void* d_out, int out_size, void* d_ws, size_t ws_size,
                              hipStream_t stream) {
    const float* flux      = (const float*)d_in[0];
    const float* scalars   = (const float*)d_in[1];
    const float* conv1_w   = (const float*)d_in[2];
    const float* bn1_g     = (const float*)d_in[3];
    const float* bn1_b     = (const float*)d_in[4];
    const float* conv2_w   = (const float*)d_in[5];
    const float* bn2_g     = (const float*)d_in[6];
    const float* bn2_b     = (const float*)d_in[7];
    const float* proj_w1   = (const float*)d_in[8];
    const float* proj_b1   = (const float*)d_in[9];
    const float* proj_w2   = (const float*)d_in[10];
    const float* proj_b2   = (const float*)d_in[11];
    const float* q_weights = (const float*)d_in[12];
    const float* head_w1   = (const float*)d_in[13];
    const float* head_b1   = (const float*)d_in[14];
    const float* head_bn_g = (const float*)d_in[15];
    const float* head_bn_b = (const float*)d_in[16];
    const float* head_w2   = (const float*)d_in[17];
    const float* head_b2   = (const float*)d_in[18];

    const int B = in_sizes[0] / L0;   // 4096

    aec_fused_kernel<<<dim3(B), dim3(256), 0, stream>>>(
        flux, scalars, conv1_w, bn1_g, bn1_b, conv2_w, bn2_g, bn2_b,
        proj_w1, proj_b1, proj_w2, proj_b2, q_weights,
        head_w1, head_b1, head_bn_g, head_bn_b, head_w2, head_b2,
        (float*)d_out);
}

// Round 2
// 307.212 us; speedup vs baseline: 1.1487x; 1.1487x over previous
//
#include <hip/hip_runtime.h>
#include <math.h>

// Problem constants (fixed by reference setup_inputs)
#define L0   4448   // flux length
#define L1P  278    // after conv1(stride4,pad7)->1112 then maxpool4
#define L2   139    // after conv2(stride2,pad3) on 278
#define NQ   8
#define NL   3
#define SD   256

#define H1S  292    // h1 row stride (words); 292%32=4 -> 2-way write aliasing only
#define H2S  145    // h2 row stride (words); odd -> spread

__global__ __launch_bounds__(256, 4)
void aec_fused_kernel(const float* __restrict__ flux,
                      const float* __restrict__ scalars,
                      const float* __restrict__ conv1_w,
                      const float* __restrict__ bn1_g, const float* __restrict__ bn1_b,
                      const float* __restrict__ conv2_w,
                      const float* __restrict__ bn2_g, const float* __restrict__ bn2_b,
                      const float* __restrict__ proj_w1, const float* __restrict__ proj_b1,
                      const float* __restrict__ proj_w2, const float* __restrict__ proj_b2,
                      const float* __restrict__ qw,
                      const float* __restrict__ head_w1, const float* __restrict__ head_b1,
                      const float* __restrict__ head_bn_g, const float* __restrict__ head_bn_b,
                      const float* __restrict__ head_w2, const float* __restrict__ head_b2,
                      float* __restrict__ out)
{
    const int b   = blockIdx.x;
    const int tid = threadIdx.x;

    // h1 [16][292] (x stored at word ic*292+4+x, x in [-4,283] zero-padded);
    // after stage2: feat[0..255], cre[256..511], cim[512..767]
    __shared__ __align__(16) float Bb[4680];
    // h2 [32][145]
    __shared__ __align__(16) float A[4640];
    __shared__ float s_U[NL * NQ * 8];
    __shared__ float s_hidden[64];
    __shared__ float s_red[32];
    __shared__ float s_q[8];
    __shared__ float s_hid2[32];

    const float BN_RSQ = 0.9999950000374997f;     // 1/sqrt(1+1e-5)

    // ---------------- stage 0: zero h1 pads (no barrier needed: disjoint words,
    // first read of pads is after the stage1->stage2 barrier) ----------------
    if (tid < 160) {
        int ic = tid / 10, w = tid - ic * 10;
        int off = (w < 4) ? w : (278 + w);        // words {0..3} and {282..287}
        Bb[ic * H1S + off] = 0.0f;
    }

    // ---------------- stage 1: conv1 + bn + relu + maxpool4 -> h1 ----------------
    // 2 channels/thread: c2 = tid&7 -> {c2, c2+8}; window slot = tid>>3 (8/wave,
    // 8 lanes share each window -> coalesced global reads, VMEM pipe not LDS)
    {
        const int c2   = tid & 7;
        const int slot = tid >> 3;
        const float* frow = flux + (size_t)b * L0;
        float wt0[15], wt1[15];
        #pragma unroll
        for (int k = 0; k < 15; ++k) {
            wt0[k] = conv1_w[c2 * 15 + k];
            wt1[k] = conv1_w[(c2 + 8) * 15 + k];
        }
        const float sc0 = bn1_g[c2] * BN_RSQ,     bt0 = bn1_b[c2];
        const float sc1 = bn1_g[c2 + 8] * BN_RSQ, bt1 = bn1_b[c2 + 8];

        for (int p = slot; p < L1P; p += 32) {
            // win[i] <-> flux idx x = 16p - 8 + i, i in [0,32); taps use i 1..27
            float win[32];
            if (p == 0) {
                #pragma unroll
                for (int i = 0; i < 8; ++i) win[i] = 0.0f;        // x<0: left pad
                const float4* src = (const float4*)frow;
                #pragma unroll
                for (int v = 0; v < 6; ++v) {
                    float4 t4 = src[v];
                    win[8+4*v] = t4.x; win[9+4*v] = t4.y; win[10+4*v] = t4.z; win[11+4*v] = t4.w;
                }
            } else if (p == L1P - 1) {
                const float4* src = (const float4*)(frow + 16 * p - 8);
                #pragma unroll
                for (int v = 0; v < 6; ++v) {
                    float4 t4 = src[v];
                    win[4*v] = t4.x; win[1+4*v] = t4.y; win[2+4*v] = t4.z; win[3+4*v] = t4.w;
                }
                #pragma unroll
                for (int i = 24; i < 32; ++i) win[i] = 0.0f;      // x>=4448: right pad
            } else {
                const float4* src = (const float4*)(frow + 16 * p - 8);
                #pragma unroll
                for (int v = 0; v < 8; ++v) {
                    float4 t4 = src[v];
                    win[4*v] = t4.x; win[1+4*v] = t4.y; win[2+4*v] = t4.z; win[3+4*v] = t4.w;
                }
            }
            float m0 = 0.0f, m1 = 0.0f;   // relu outputs >= 0
            #pragma unroll
            for (int j2 = 0; j2 < 4; ++j2) {
                float a0 = 0.0f, a1 = 0.0f;
                #pragma unroll
                for (int k = 0; k < 15; ++k) {
                    float wv = win[4*j2 + 1 + k];
                    a0 += wv * wt0[k];
                    a1 += wv * wt1[k];
                }
                m0 = fmaxf(m0, fmaxf(a0 * sc0 + bt0, 0.0f));
                m1 = fmaxf(m1, fmaxf(a1 * sc1 + bt1, 0.0f));
            }
            Bb[c2 * H1S + 4 + p]       = m0;
            Bb[(c2 + 8) * H1S + 4 + p] = m1;
        }
    }

    // gate matrices (write before the next barrier; read after stage2 barrier)
    if (tid < NL * NQ) {
        float phi = qw[tid * 3 + 0], th = qw[tid * 3 + 1], om = qw[tid * 3 + 2];
        float ch = cosf(0.5f * th), sh = sinf(0.5f * th);
        float a  = 0.5f * (phi + om), bb = 0.5f * (phi - om);
        float ca = cosf(a), sa = sinf(a), cb = cosf(bb), sb = sinf(bb);
        float* U = &s_U[tid * 8];
        U[0] =  ca * ch; U[1] = -sa * ch;   // U00
        U[2] = -cb * sh; U[3] = -sb * sh;   // U01
        U[4] =  cb * sh; U[5] = -sb * sh;   // U10
        U[6] =  ca * ch; U[7] =  sa * ch;   // U11
    }
    __syncthreads();

    // ---------------- stage 2: conv2 + bn + relu -> h2 ----------------
    // 2 channels/thread: c2 = tid&15 -> {c2, c2+16}; g = tid>>4 -> even j0,
    // npos in {8,10,5}. Windows: 7 aligned b128 from LDS (4 distinct/wave,
    // banks disjoint). Weights: float2 chunks straight from global (L1-hot).
    {
        const int c2 = tid & 15;
        const int g  = tid >> 4;
        const int j0   = (9 * g) & ~1;
        const int j1e  = (g == 15) ? L2 : ((9 * (g + 1)) & ~1);
        const int npos = j1e - j0;                 // 8, 10, or 5
        float acc0[10], acc1[10];
        #pragma unroll
        for (int r = 0; r < 10; ++r) { acc0[r] = 0.0f; acc1[r] = 0.0f; }

        #pragma unroll 1
        for (int t = 0; t < 8; ++t) {              // ic chunk of 2
            float wt0[14], wt1[14];
            const float2* w0 = (const float2*)(conv2_w + c2 * 112 + t * 14);
            const float2* w1 = (const float2*)(conv2_w + (c2 + 16) * 112 + t * 14);
            #pragma unroll
            for (int m = 0; m < 7; ++m) {
                float2 a2 = w0[m]; wt0[2*m] = a2.x; wt0[2*m+1] = a2.y;
                float2 b2 = w1[m]; wt1[2*m] = b2.x; wt1[2*m+1] = b2.y;
            }
            #pragma unroll
            for (int u = 0; u < 2; ++u) {
                const int ic = 2 * t + u;
                // win[i] <-> x = 2*j0 - 4 + i; tap (jj,k) -> i = 1 + 2*jj + k
                float win[28];
                const float4* src = (const float4*)(Bb + ic * H1S + 2 * j0);
                #pragma unroll
                for (int v = 0; v < 7; ++v) {
                    float4 t4 = src[v];
                    win[4*v] = t4.x; win[1+4*v] = t4.y; win[2+4*v] = t4.z; win[3+4*v] = t4.w;
                }
                #pragma unroll
                for (int jj = 0; jj < 10; ++jj) {
                    float s0 = 0.0f, s1 = 0.0f;
                    #pragma unroll
                    for (int k = 0; k < 7; ++k) {
                        float wv = win[1 + 2*jj + k];
                        s0 += wt0[u*7 + k] * wv;
                        s1 += wt1[u*7 + k] * wv;
                    }
                    acc0[jj] += s0;
                    acc1[jj] += s1;
                }
            }
        }
        const float sc0 = bn2_g[c2] * BN_RSQ,      bt0 = bn2_b[c2];
        const float sc1 = bn2_g[c2 + 16] * BN_RSQ, bt1 = bn2_b[c2 + 16];
        #pragma unroll
        for (int jj = 0; jj < 10; ++jj) {
            if (jj < npos) {
                A[c2 * H2S + j0 + jj]        = fmaxf(acc0[jj] * sc0 + bt0, 0.0f);
                A[(c2 + 16) * H2S + j0 + jj] = fmaxf(acc1[jj] * sc1 + bt1, 0.0f);
            }
        }
    }
    __syncthreads();

    // ---------------- stage 3: adaptive avg pool -> feat (Bb[0..255]) ----------------
    {
        const int c = tid >> 3, i = tid & 7;
        const int s0 = (i * L2) >> 3;
        const int e0 = ((i + 1) * L2 + 7) >> 3;   // ceil
        float sum = 0.0f;
        for (int j = s0; j < e0; ++j) sum += A[c * H2S + j];
        Bb[tid] = sum / (float)(e0 - s0);         // feat[c*8+i]
    }
    __syncthreads();

    // ---------------- stage 4: proj1 (256 -> 64), relu ----------------
    {
        const int o = tid >> 2, s = tid & 3;
        const float4* wg = (const float4*)(proj_w1 + 64 * tid);   // == o*256 + s*64
        const float4* xf = (const float4*)(Bb + 64 * s);
        float acc = 0.0f;
        #pragma unroll
        for (int t = 0; t < 16; ++t) {
            float4 w4 = wg[t], x4 = xf[t];
            acc += w4.x * x4.x + w4.y * x4.y + w4.z * x4.z + w4.w * x4.w;
        }
        acc += __shfl_down(acc, 2, 64);
        acc += __shfl_down(acc, 1, 64);
        if (s == 0) s_hidden[o] = fmaxf(acc + proj_b1[o], 0.0f);
    }
    __syncthreads();

    // ---------------- proj2 (64 -> 256) + L2 normalize -> amplitude per thread ----
    float re, im;
    {
        const float4* wg = (const float4*)(proj_w2 + 64 * tid);
        const float4* hf = (const float4*)s_hidden;
        float acc = proj_b2[tid];
        #pragma unroll
        for (int t = 0; t < 16; ++t) {
            float4 w4 = wg[t], x4 = hf[t];
            acc += w4.x * x4.x + w4.y * x4.y + w4.z * x4.z + w4.w * x4.w;
        }
        float ss = acc * acc;
        #pragma unroll
        for (int off = 32; off >= 1; off >>= 1) ss += __shfl_xor(ss, off, 64);
        if ((tid & 63) == 0) s_red[tid >> 6] = ss;
        __syncthreads();
        float sst = s_red[0] + s_red[1] + s_red[2] + s_red[3];
        float n   = sqrtf(sst);
        float inv = 1.0f / fmaxf(n, 1e-12f);
        float xi  = acc * inv;
        if (n * inv < 1e-8f) xi = 0.0625f;        // uniform 1/sqrt(256)
        re = xi; im = 0.0f;
    }

    // ---------------- quantum circuit: one amplitude per thread ----------------
    float* s_cre = &Bb[256];
    float* s_cim = &Bb[512];
    #pragma unroll 1
    for (int l = 0; l < NL; ++l) {
        #pragma unroll
        for (int q = 0; q < NQ; ++q) {
            const float* U = &s_U[(l * NQ + q) * 8];
            const float u00r = U[0], u00i = U[1], u01r = U[2], u01i = U[3];
            const float u10r = U[4], u10i = U[5], u11r = U[6], u11i = U[7];
            const int bp = 7 - q;                 // wire 0 = MSB
            float pre, pim;
            if (bp >= 6) {                        // cross-wave partner: LDS
                s_cre[tid] = re; s_cim[tid] = im;
                __syncthreads();
                const int pidx = tid ^ (1 << bp);
                pre = s_cre[pidx]; pim = s_cim[pidx];
                __syncthreads();
            } else {                              // in-wave partner: shuffle
                pre = __shfl_xor(re, 1 << bp, 64);
                pim = __shfl_xor(im, 1 << bp, 64);
            }
            const int bit = (tid >> bp) & 1;
            const float csr = bit ? u11r : u00r;
            const float csi = bit ? u11i : u00i;
            const float cpr = bit ? u10r : u01r;
            const float cpi = bit ? u10i : u01i;
            const float nr = csr * re - csi * im + cpr * pre - cpi * pim;
            const float ni = csr * im + csi * re + cpr * pim + cpi * pre;
            re = nr; im = ni;
        }
        // CNOT ring composed into one permutation: new[i] = psi[f0(f1(...f7(i)))]
        int src = tid;
        #pragma unroll
        for (int q = 7; q >= 0; --q) {
            const int cb = 7 - q;
            const int tb = 7 - ((q + 1) & 7);
            src ^= ((src >> cb) & 1) << tb;
        }
        s_cre[tid] = re; s_cim[tid] = im;
        __syncthreads();
        re = s_cre[src]; im = s_cim[src];
        __syncthreads();
    }

    // ---------------- Z expectations ----------------
    {
        const float pr = re * re + im * im;
        float zv[8];
        #pragma unroll
        for (int q = 0; q < 8; ++q) zv[q] = ((tid >> (7 - q)) & 1) ? -pr : pr;
        #pragma unroll
        for (int off = 32; off >= 1; off >>= 1) {
            #pragma unroll
            for (int q = 0; q < 8; ++q) zv[q] += __shfl_xor(zv[q], off, 64);
        }
        if ((tid & 63) == 0) {
            const int wid = tid >> 6;
            #pragma unroll
            for (int q = 0; q < 8; ++q) s_red[wid * 8 + q] = zv[q];
        }
        __syncthreads();
        if (tid < 8)
            s_q[tid] = s_red[tid] + s_red[8 + tid] + s_red[16 + tid] + s_red[24 + tid];
        __syncthreads();
    }

    // ---------------- head ----------------
    if (tid < 32) {
        float acc = head_b1[tid];
        #pragma unroll
        for (int k = 0; k < 8; ++k) acc += head_w1[tid * 14 + k] * s_q[k];
        #pragma unroll
        for (int k = 0; k < 6; ++k) acc += head_w1[tid * 14 + 8 + k] * scalars[b * 6 + k];
        float h = fmaxf(acc * (head_bn_g[tid] * BN_RSQ) + head_bn_b[tid], 0.0f);
        s_hid2[tid] = h;
    }
    __syncthreads();
    if (tid < 3) {
        float acc = head_b2[tid];
        #pragma unroll
        for (int k = 0; k < 32; ++k) acc += head_w2[tid * 32 + k] * s_hid2[k];
        out[b * 3 + tid] = acc;
    }
}

extern "C" void kernel_launch(void* const* d_in, const int* in_sizes, int n_in,
                              void* d_out, int out_size, void* d_ws, size_t ws_size,
                              hipStream_t stream) {
    const float* flux      = (const float*)d_in[0];
    const float* scalars   = (const float*)d_in[1];
    const float* conv1_w   = (const float*)d_in[2];
    const float* bn1_g     = (const float*)d_in[3];
    const float* bn1_b     = (const float*)d_in[4];
    const float* conv2_w   = (const float*)d_in[5];
    const float* bn2_g     = (const float*)d_in[6];
    const float* bn2_b     = (const float*)d_in[7];
    const float* proj_w1   = (const float*)d_in[8];
    const float* proj_b1   = (const float*)d_in[9];
    const float* proj_w2   = (const float*)d_in[10];
    const float* proj_b2   = (const float*)d_in[11];
    const float* q_weights = (const float*)d_in[12];
    const float* head_w1   = (const float*)d_in[13];
    const float* head_b1   = (const float*)d_in[14];
    const float* head_bn_g = (const float*)d_in[15];
    const float* head_bn_b = (const float*)d_in[16];
    const float* head_w2   = (const float*)d_in[17];
    const float* head_b2   = (const float*)d_in[18];

    const int B = in_sizes[0] / L0;   // 4096

    aec_fused_kernel<<<dim3(B), dim3(256), 0, stream>>>(
        flux, scalars, conv1_w, bn1_g, bn1_b, conv2_w, bn2_g, bn2_b,
        proj_w1, proj_b1, proj_w2, proj_b2, q_weights,
        head_w1, head_b1, head_bn_g, head_bn_b, head_w2, head_b2,
        (float*)d_out);
}